// Round 10
// baseline (124.457 us; speedup 1.0000x reference)
//
#include <hip/hip_runtime.h>
#include <hip/hip_fp16.h>

#define SEQ   2048
#define BATCH 256
#define ED    16
#define NW    16
#define HD    16
#define TAGS  64
#define S4    (SEQ/4)

// chunked recurrence: 64 chunks x 8 s4-groups (32 steps) emitted each,
// warmed up from zero state for 8 s4-groups (32 steps).
// f = sigmoid(cos(.)) <= sigmoid(1) = 0.731 guarantees geometric forgetting;
// (warm 128/64/32 all empirically identical at absmax 0.03125).
#define NCHUNK   64
#define CH_S4    (S4 / NCHUNK)    // 8
#define WARM_S4  8

typedef unsigned int uint32;

// DPP cross-lane move, compile-time ctrl. quad_perm/row_half_mirror/row_ror:8
// are xor-type (direction-unambiguous); row_ror:1/2/4 are used only inside
// commutative reductions where rotation direction is irrelevant.
#define DPPF(src, ctrl) \
    __int_as_float(__builtin_amdgcn_mov_dpp(__float_as_int(src), (ctrl), 0xF, 0xF, false))

// dot of two 16-float register arrays, 4 accumulators
__device__ __forceinline__ float dot16aa(const float* x, const float* w, float init) {
    float a0 = fmaf(x[0], w[0], init);
    float a1 = x[1] * w[1];
    float a2 = x[2] * w[2];
    float a3 = x[3] * w[3];
    a0 = fmaf(x[4],  w[4],  a0);
    a1 = fmaf(x[5],  w[5],  a1);
    a2 = fmaf(x[6],  w[6],  a2);
    a3 = fmaf(x[7],  w[7],  a3);
    a0 = fmaf(x[8],  w[8],  a0);
    a1 = fmaf(x[9],  w[9],  a1);
    a2 = fmaf(x[10], w[10], a2);
    a3 = fmaf(x[11], w[11], a3);
    a0 = fmaf(x[12], w[12], a0);
    a1 = fmaf(x[13], w[13], a1);
    a2 = fmaf(x[14], w[14], a2);
    a3 = fmaf(x[15], w[15], a3);
    return (a0 + a1) + (a2 + a3);
}

// ---------------------------------------------------------------------------
// Kernel A: enc = cos(emb[tok] @ W_eq^T + b_eq + theta) ;
//           px[b][s4][j][g][q0..q3] = enc @ Wx^T + b + theta   (fp16, radians)
// Stores issued in layout order: per j, 4 gates packed into 2x uint4 ->
// sequential 16B stores, 512B contiguous per thread (full 32B sectors,
// no write inflation).
// ---------------------------------------------------------------------------
__global__ __launch_bounds__(256) void encode_px_kernel(
    const int* __restrict__ sentence, const float* __restrict__ emb,
    const float* __restrict__ w_eq, const float* __restrict__ b_eq, const float* __restrict__ thc,
    const float* __restrict__ w_f, const float* __restrict__ b_f, const float* __restrict__ th_f,
    const float* __restrict__ w_i, const float* __restrict__ b_i, const float* __restrict__ th_i,
    const float* __restrict__ w_u, const float* __restrict__ b_u, const float* __restrict__ th_u,
    const float* __restrict__ w_o, const float* __restrict__ b_o, const float* __restrict__ th_o,
    __half* __restrict__ px)
{
    __shared__ float swq[ED * NW];
    __shared__ float sbt1[NW];
    __shared__ float swx[4 * NW * ED];   // [g][j][k]
    __shared__ float sbt2[4 * NW];       // [g][j]

    const int tid = threadIdx.x;
    swq[tid] = w_eq[tid];
    if (tid < NW) sbt1[tid] = b_eq[tid] + thc[tid];
    for (int idx = tid; idx < 4 * NW * ED; idx += 256) {
        int g = idx >> 8; int j = (idx >> 4) & 15; int k = idx & 15;
        const float* ws = (g == 0) ? w_f : (g == 1) ? w_i : (g == 2) ? w_u : w_o;
        swx[idx] = ws[j * 32 + k];
    }
    if (tid < 64) {
        int g = tid >> 4; int j = tid & 15;
        const float* bs = (g == 0) ? b_f : (g == 1) ? b_i : (g == 2) ? b_u : b_o;
        const float* ts = (g == 0) ? th_f : (g == 1) ? th_i : (g == 2) ? th_u : th_o;
        sbt2[tid] = bs[j] + ts[j];
    }
    __syncthreads();

    const int e4 = blockIdx.x * 256 + tid;
    const int s4 = e4 >> 8;
    const int b  = e4 & 255;

    float e[4][ED];
    #pragma unroll
    for (int q = 0; q < 4; q++) {
        const int s   = s4 * 4 + q;
        const int tok = sentence[s * BATCH + b];
        const float4* ep = (const float4*)(emb + (size_t)tok * ED);
        float4 v0 = ep[0], v1 = ep[1], v2 = ep[2], v3 = ep[3];
        e[q][0]  = v0.x; e[q][1]  = v0.y; e[q][2]  = v0.z; e[q][3]  = v0.w;
        e[q][4]  = v1.x; e[q][5]  = v1.y; e[q][6]  = v1.z; e[q][7]  = v1.w;
        e[q][8]  = v2.x; e[q][9]  = v2.y; e[q][10] = v2.z; e[q][11] = v2.w;
        e[q][12] = v3.x; e[q][13] = v3.y; e[q][14] = v3.z; e[q][15] = v3.w;
    }

    float enc[4][NW];
    #pragma unroll
    for (int j = 0; j < NW; j++) {
        float wrow[16];
        {
            const float4* w4 = (const float4*)swq + j * 4;
            float4 w0 = w4[0], w1 = w4[1], w2 = w4[2], w3 = w4[3];
            wrow[0]  = w0.x; wrow[1]  = w0.y; wrow[2]  = w0.z; wrow[3]  = w0.w;
            wrow[4]  = w1.x; wrow[5]  = w1.y; wrow[6]  = w1.z; wrow[7]  = w1.w;
            wrow[8]  = w2.x; wrow[9]  = w2.y; wrow[10] = w2.z; wrow[11] = w2.w;
            wrow[12] = w3.x; wrow[13] = w3.y; wrow[14] = w3.z; wrow[15] = w3.w;
        }
        const float bt = sbt1[j];
        #pragma unroll
        for (int q = 0; q < 4; q++)
            enc[q][j] = __cosf(dot16aa(e[q], wrow, bt));
    }

    // phase 2: px in [j][g][q] layout, stores in layout order
    __half* pxp = px + ((size_t)b * S4 + s4) * 256;
    for (int j = 0; j < 16; j++) {
        uint2 pk[4];
        #pragma unroll
        for (int g = 0; g < 4; g++) {
            const int gj = g * 16 + j;
            float wrow[16];
            {
                const float4* w4 = (const float4*)swx + gj * 4;
                float4 w0 = w4[0], w1 = w4[1], w2 = w4[2], w3 = w4[3];
                wrow[0]  = w0.x; wrow[1]  = w0.y; wrow[2]  = w0.z; wrow[3]  = w0.w;
                wrow[4]  = w1.x; wrow[5]  = w1.y; wrow[6]  = w1.z; wrow[7]  = w1.w;
                wrow[8]  = w2.x; wrow[9]  = w2.y; wrow[10] = w2.z; wrow[11] = w2.w;
                wrow[12] = w3.x; wrow[13] = w3.y; wrow[14] = w3.z; wrow[15] = w3.w;
            }
            const float bt = sbt2[gj];
            float a0 = dot16aa(enc[0], wrow, bt);
            float a1 = dot16aa(enc[1], wrow, bt);
            float a2 = dot16aa(enc[2], wrow, bt);
            float a3 = dot16aa(enc[3], wrow, bt);
            __half2 lo = __floats2half2_rn(a0, a1);
            __half2 hi = __floats2half2_rn(a2, a3);
            pk[g].x = *(uint32*)&lo;
            pk[g].y = *(uint32*)&hi;
        }
        uint4 s0, s1;
        s0.x = pk[0].x; s0.y = pk[0].y; s0.z = pk[1].x; s0.w = pk[1].y;
        s1.x = pk[2].x; s1.y = pk[2].y; s1.z = pk[3].x; s1.w = pk[3].y;
        uint4* dst = (uint4*)pxp + j * 2;
        dst[0] = s0;
        dst[1] = s1;
    }
}

// ---------------------------------------------------------------------------
// Kernel B: fused recurrence + tag head. 256-thread workgroups = 4
// INDEPENDENT waves (no barriers, no LDS); wave w of block handles
// wid = blockIdx.x*4 + w -> (chunk, b4). Packing 4 waves/wg works around
// the per-CU residency shortfall seen with 1-wave workgroups (R7/R9:
// ~6 waves/CU resident despite 16 available).
// Within a wave: row r (16 lanes) = batch b4*4+r; lane j owns all four
// gates of unit j; h-allgather = row-local XMAP DPP network; tag head:
// lane j computes tags 4j..4j+3; softmax sum via row_ror DPP allreduce;
// float4 store -> contiguous 1KB per wave.
// launch_bounds min-waves MUST stay low (VGPR>=96 needed; (64,4)-style
// clamping spilled wrot/wtp in R8: FETCH 48MB -> 1.04GB).
// ---------------------------------------------------------------------------
__global__ __launch_bounds__(256, 2) void lstm_tag_kernel(
    const __half* __restrict__ px,
    const float* __restrict__ w_f, const float* __restrict__ w_i,
    const float* __restrict__ w_u, const float* __restrict__ w_o,
    const float* __restrict__ w_tag, const float* __restrict__ b_tag,
    float* __restrict__ out)
{
    const int lane  = threadIdx.x & 63;
    const int wid   = blockIdx.x * 4 + (threadIdx.x >> 6);  // 0..4095
    const int row   = lane >> 4;          // batch sub-index within wave
    const int j     = lane & 15;          // hidden unit
    const int chunk = wid >> 6;           // 64 chunks
    const int b4    = wid & 63;           // group of 4 batches
    const int b     = b4 * 4 + row;

    // xor map of the DPP allgather network (stages: ^1, ^2, ^7, ^8)
    const int XMAP[16] = {0,1,2,3,7,6,5,4,8,9,10,11,15,14,13,12};

    // h-weights for all 4 gates of unit j, XMAP order (j-dependent only)
    float wrot[4][16];
    {
        const float* wsrc[4] = {w_f, w_i, w_u, w_o};
        #pragma unroll
        for (int g = 0; g < 4; g++)
            #pragma unroll
            for (int m = 0; m < 16; m++)
                wrot[g][m] = wsrc[g][j * 32 + 16 + (j ^ XMAP[m])];
    }
    // tag weights for tags 4j..4j+3, XMAP order
    float wtp[4][16];
    float btag[4];
    #pragma unroll
    for (int t = 0; t < 4; t++) {
        #pragma unroll
        for (int m = 0; m < 16; m++)
            wtp[t][m] = w_tag[(j * 4 + t) * 16 + (j ^ XMAP[m])];
        btag[t] = b_tag[j * 4 + t];
    }

    const int start_s4 = chunk * CH_S4;
    const int warm_s4  = (chunk == 0) ? 0 : (start_s4 - WARM_S4);
    const int end_s4   = start_s4 + CH_S4;
    const int emit0    = start_s4 * 4;     // first emitted timestep

    float c = 0.f;
    float h = 0.f;

    // px: per (b,s4) 512B block; lane j reads 32B at offset j*32
    const uint4* pba = (const uint4*)px + ((size_t)b * S4 + warm_s4) * 32 + j * 2;
    uint4 curA = pba[0], curB = pba[1];
    const int niters = end_s4 - warm_s4;

    float* outp = out + ((size_t)emit0 * BATCH + b) * TAGS + j * 4;

#define ALLGATHER(v0n) \
    float v0 = (v0n); \
    float v1 = DPPF(v0, 0xB1); \
    float v2 = DPPF(v0, 0x4E); \
    float v3 = DPPF(v1, 0x4E); \
    float v4 = DPPF(v0, 0x141); \
    float v5 = DPPF(v1, 0x141); \
    float v6 = DPPF(v2, 0x141); \
    float v7 = DPPF(v3, 0x141); \
    float v8  = DPPF(v0, 0x128); \
    float v9  = DPPF(v1, 0x128); \
    float v10 = DPPF(v2, 0x128); \
    float v11 = DPPF(v3, 0x128); \
    float v12 = DPPF(v4, 0x128); \
    float v13 = DPPF(v5, 0x128); \
    float v14 = DPPF(v6, 0x128); \
    float v15 = DPPF(v7, 0x128)

#define DOT16V(w, init, res) do { \
    float a0 = fmaf(v0, (w)[0], (init)); \
    float a1 = v1 * (w)[1]; \
    float a2 = v2 * (w)[2]; \
    float a3 = v3 * (w)[3]; \
    a0 = fmaf(v4,  (w)[4],  a0); \
    a1 = fmaf(v5,  (w)[5],  a1); \
    a2 = fmaf(v6,  (w)[6],  a2); \
    a3 = fmaf(v7,  (w)[7],  a3); \
    a0 = fmaf(v8,  (w)[8],  a0); \
    a1 = fmaf(v9,  (w)[9],  a1); \
    a2 = fmaf(v10, (w)[10], a2); \
    a3 = fmaf(v11, (w)[11], a3); \
    a0 = fmaf(v12, (w)[12], a0); \
    a1 = fmaf(v13, (w)[13], a1); \
    a2 = fmaf(v14, (w)[14], a2); \
    a3 = fmaf(v15, (w)[15], a3); \
    (res) = (a0 + a1) + (a2 + a3); \
} while (0)

#define TAG_EMIT() do { \
    float lg0, lg1, lg2, lg3; \
    DOT16V(wtp[0], btag[0], lg0); \
    DOT16V(wtp[1], btag[1], lg1); \
    DOT16V(wtp[2], btag[2], lg2); \
    DOT16V(wtp[3], btag[3], lg3); \
    float p = (__expf(lg0) + __expf(lg1)) + (__expf(lg2) + __expf(lg3)); \
    p += DPPF(p, 0x121);   /* row_ror:1 */ \
    p += DPPF(p, 0x122);   /* row_ror:2 */ \
    p += DPPF(p, 0x124);   /* row_ror:4 */ \
    p += DPPF(p, 0x128);   /* row_ror:8 */ \
    const float lp = __logf(p); \
    float4 ov = make_float4(lg0 - lp, lg1 - lp, lg2 - lp, lg3 - lp); \
    *(float4*)outp = ov; \
    outp += (size_t)BATCH * TAGS; \
} while (0)

    for (int it = 0; it < niters; it++) {
        const int nidx = (it < niters - 1) ? (it + 1) : it;
        uint4 nxtA = pba[(size_t)nidx * 32];
        uint4 nxtB = pba[(size_t)nidx * 32 + 1];

        const int sg_base = (warm_s4 + it) * 4;

        #pragma unroll
        for (int q = 0; q < 4; q++) {
            // ---- unpack px for all 4 gates at this q ----
            float pxq[4];
            if (q == 0) {
                pxq[0] = __low2float(*(__half2*)&curA.x);
                pxq[1] = __low2float(*(__half2*)&curA.z);
                pxq[2] = __low2float(*(__half2*)&curB.x);
                pxq[3] = __low2float(*(__half2*)&curB.z);
            } else if (q == 1) {
                pxq[0] = __high2float(*(__half2*)&curA.x);
                pxq[1] = __high2float(*(__half2*)&curA.z);
                pxq[2] = __high2float(*(__half2*)&curB.x);
                pxq[3] = __high2float(*(__half2*)&curB.z);
            } else if (q == 2) {
                pxq[0] = __low2float(*(__half2*)&curA.y);
                pxq[1] = __low2float(*(__half2*)&curA.w);
                pxq[2] = __low2float(*(__half2*)&curB.y);
                pxq[3] = __low2float(*(__half2*)&curB.w);
            } else {
                pxq[0] = __high2float(*(__half2*)&curA.y);
                pxq[1] = __high2float(*(__half2*)&curA.w);
                pxq[2] = __high2float(*(__half2*)&curB.y);
                pxq[3] = __high2float(*(__half2*)&curB.w);
            }

            // ---- allgather h_{t-1} across each 16-lane row ----
            ALLGATHER(h);

            // ---- tag head for previous timestep (off the serial chain) ----
            const int sg = sg_base + q;
            if (sg > emit0) TAG_EMIT();

            // ---- 4 gate pre-activations (all in-lane, full ILP) ----
            float pre0, pre1, pre2, pre3;
            DOT16V(wrot[0], pxq[0], pre0);
            DOT16V(wrot[1], pxq[1], pre1);
            DOT16V(wrot[2], pxq[2], pre2);
            DOT16V(wrot[3], pxq[3], pre3);

            // ---- activations: f,i,o sigmoid(cos); u tanh(cos) ----
            const float cv0 = __cosf(pre0);
            const float cv1 = __cosf(pre1);
            const float cv2 = __cosf(pre2);
            const float cv3 = __cosf(pre3);
            const float fv = __builtin_amdgcn_rcpf(1.f + __expf(-cv0));
            const float iv = __builtin_amdgcn_rcpf(1.f + __expf(-cv1));
            const float uv = fmaf(2.f, __builtin_amdgcn_rcpf(1.f + __expf(-2.f * cv2)), -1.f);
            const float ov = __builtin_amdgcn_rcpf(1.f + __expf(-cv3));

            // ---- state update (once per lane) ----
            c = fmaf(fv, c, iv * uv);
            const float th = fmaf(2.f, __builtin_amdgcn_rcpf(1.f + __expf(-2.f * c)), -1.f);
            h = ov * th;
        }
        curA = nxtA;
        curB = nxtB;
    }

    // epilogue: tag for the chunk's final timestep
    {
        ALLGATHER(h);
        TAG_EMIT();
    }
#undef ALLGATHER
#undef DOT16V
#undef TAG_EMIT
}

extern "C" void kernel_launch(void* const* d_in, const int* in_sizes, int n_in,
                              void* d_out, int out_size, void* d_ws, size_t ws_size,
                              hipStream_t stream) {
    const int*   sentence = (const int*)d_in[0];
    const float* emb   = (const float*)d_in[1];
    const float* w_eq  = (const float*)d_in[2];
    const float* b_eq  = (const float*)d_in[3];
    const float* thc   = (const float*)d_in[4];
    const float* w_f   = (const float*)d_in[5];
    const float* b_f   = (const float*)d_in[6];
    const float* th_f  = (const float*)d_in[7];
    const float* w_i   = (const float*)d_in[8];
    const float* b_i   = (const float*)d_in[9];
    const float* th_i  = (const float*)d_in[10];
    const float* w_u   = (const float*)d_in[11];
    const float* b_u   = (const float*)d_in[12];
    const float* th_u  = (const float*)d_in[13];
    const float* w_o   = (const float*)d_in[14];
    const float* b_o   = (const float*)d_in[15];
    const float* th_o  = (const float*)d_in[16];
    const float* w_tag = (const float*)d_in[17];
    const float* b_tag = (const float*)d_in[18];

    __half* pxw = (__half*)d_ws;                 // 67,108,864 B
    float*  out = (float*)d_out;

    encode_px_kernel<<<dim3((S4 * BATCH) / 256), dim3(256), 0, stream>>>(
        sentence, emb, w_eq, b_eq, thc,
        w_f, b_f, th_f, w_i, b_i, th_i, w_u, b_u, th_u, w_o, b_o, th_o, pxw);
    lstm_tag_kernel<<<dim3(NCHUNK * (BATCH / 4) / 4), dim3(256), 0, stream>>>(
        pxw, w_f, w_i, w_u, w_o, w_tag, b_tag, out);
}

// Round 11
// 114.211 us; speedup vs baseline: 1.0897x; 1.0897x over previous
//
#include <hip/hip_runtime.h>
#include <hip/hip_fp16.h>

#define SEQ   2048
#define BATCH 256
#define ED    16
#define NW    16
#define HD    16
#define TAGS  64
#define S4    (SEQ/4)

// chunked recurrence: 64 chunks x 8 s4-groups (32 steps) emitted each,
// warmed up from zero state for 8 s4-groups (32 steps).
// f = sigmoid(cos(.)) <= sigmoid(1) = 0.731 guarantees geometric forgetting;
// (warm 128/64/32 all empirically identical at absmax 0.03125).
#define NCHUNK   64
#define CH_S4    (S4 / NCHUNK)    // 8
#define WARM_S4  8

typedef unsigned int uint32;

// DPP cross-lane move, compile-time ctrl. quad_perm/row_half_mirror/row_ror:8
// are xor-type (direction-unambiguous); row_ror:1/2/4 are used only inside
// commutative reductions where rotation direction is irrelevant.
#define DPPF(src, ctrl) \
    __int_as_float(__builtin_amdgcn_mov_dpp(__float_as_int(src), (ctrl), 0xF, 0xF, false))
#define DPPI(src, ctrl) \
    ((uint32)__builtin_amdgcn_mov_dpp((int)(src), (ctrl), 0xF, 0xF, false))

__device__ __forceinline__ __half2 u2h(uint32 u) {
    __half2 h; __builtin_memcpy(&h, &u, 4); return h;
}
__device__ __forceinline__ uint32 h2u(__half2 h) {
    uint32 u; __builtin_memcpy(&u, &h, 4); return u;
}

// dot of two 16-float register arrays, 4 accumulators (encode kernel)
__device__ __forceinline__ float dot16aa(const float* x, const float* w, float init) {
    float a0 = fmaf(x[0], w[0], init);
    float a1 = x[1] * w[1];
    float a2 = x[2] * w[2];
    float a3 = x[3] * w[3];
    a0 = fmaf(x[4],  w[4],  a0);
    a1 = fmaf(x[5],  w[5],  a1);
    a2 = fmaf(x[6],  w[6],  a2);
    a3 = fmaf(x[7],  w[7],  a3);
    a0 = fmaf(x[8],  w[8],  a0);
    a1 = fmaf(x[9],  w[9],  a1);
    a2 = fmaf(x[10], w[10], a2);
    a3 = fmaf(x[11], w[11], a3);
    a0 = fmaf(x[12], w[12], a0);
    a1 = fmaf(x[13], w[13], a1);
    a2 = fmaf(x[14], w[14], a2);
    a3 = fmaf(x[15], w[15], a3);
    return (a0 + a1) + (a2 + a3);
}

// packed fp16 dot: vv[m] holds (h_A[j^x(m)], h_B[j^x(m)]); w duplicated
// per-half. Two batches per instruction; halves never mix.
__device__ __forceinline__ void dot16h(const uint32* vv, const __half2* w,
                                       __half2 init, float& rA, float& rB) {
    __half2 a0 = __hfma2(u2h(vv[0]), w[0], init);
    __half2 a1 = __hmul2(u2h(vv[1]), w[1]);
    __half2 a2 = __hmul2(u2h(vv[2]), w[2]);
    __half2 a3 = __hmul2(u2h(vv[3]), w[3]);
    a0 = __hfma2(u2h(vv[4]),  w[4],  a0);
    a1 = __hfma2(u2h(vv[5]),  w[5],  a1);
    a2 = __hfma2(u2h(vv[6]),  w[6],  a2);
    a3 = __hfma2(u2h(vv[7]),  w[7],  a3);
    a0 = __hfma2(u2h(vv[8]),  w[8],  a0);
    a1 = __hfma2(u2h(vv[9]),  w[9],  a1);
    a2 = __hfma2(u2h(vv[10]), w[10], a2);
    a3 = __hfma2(u2h(vv[11]), w[11], a3);
    a0 = __hfma2(u2h(vv[12]), w[12], a0);
    a1 = __hfma2(u2h(vv[13]), w[13], a1);
    a2 = __hfma2(u2h(vv[14]), w[14], a2);
    a3 = __hfma2(u2h(vv[15]), w[15], a3);
    a0 = __hadd2(a0, a1);
    a2 = __hadd2(a2, a3);
    a0 = __hadd2(a0, a2);
    rA = __low2float(a0);
    rB = __high2float(a0);
}

// ---------------------------------------------------------------------------
// Kernel A: enc = cos(emb[tok] @ W_eq^T + b_eq + theta) ;
//           px[b][s4][j][g][q0..q3] = enc @ Wx^T + b + theta   (fp16, radians)
// Stores issued in layout order (contiguous 512B/thread, no write inflation).
// ---------------------------------------------------------------------------
__global__ __launch_bounds__(256) void encode_px_kernel(
    const int* __restrict__ sentence, const float* __restrict__ emb,
    const float* __restrict__ w_eq, const float* __restrict__ b_eq, const float* __restrict__ thc,
    const float* __restrict__ w_f, const float* __restrict__ b_f, const float* __restrict__ th_f,
    const float* __restrict__ w_i, const float* __restrict__ b_i, const float* __restrict__ th_i,
    const float* __restrict__ w_u, const float* __restrict__ b_u, const float* __restrict__ th_u,
    const float* __restrict__ w_o, const float* __restrict__ b_o, const float* __restrict__ th_o,
    __half* __restrict__ px)
{
    __shared__ float swq[ED * NW];
    __shared__ float sbt1[NW];
    __shared__ float swx[4 * NW * ED];   // [g][j][k]
    __shared__ float sbt2[4 * NW];       // [g][j]

    const int tid = threadIdx.x;
    swq[tid] = w_eq[tid];
    if (tid < NW) sbt1[tid] = b_eq[tid] + thc[tid];
    for (int idx = tid; idx < 4 * NW * ED; idx += 256) {
        int g = idx >> 8; int j = (idx >> 4) & 15; int k = idx & 15;
        const float* ws = (g == 0) ? w_f : (g == 1) ? w_i : (g == 2) ? w_u : w_o;
        swx[idx] = ws[j * 32 + k];
    }
    if (tid < 64) {
        int g = tid >> 4; int j = tid & 15;
        const float* bs = (g == 0) ? b_f : (g == 1) ? b_i : (g == 2) ? b_u : b_o;
        const float* ts = (g == 0) ? th_f : (g == 1) ? th_i : (g == 2) ? th_u : th_o;
        sbt2[tid] = bs[j] + ts[j];
    }
    __syncthreads();

    const int e4 = blockIdx.x * 256 + tid;
    const int s4 = e4 >> 8;
    const int b  = e4 & 255;

    float e[4][ED];
    #pragma unroll
    for (int q = 0; q < 4; q++) {
        const int s   = s4 * 4 + q;
        const int tok = sentence[s * BATCH + b];
        const float4* ep = (const float4*)(emb + (size_t)tok * ED);
        float4 v0 = ep[0], v1 = ep[1], v2 = ep[2], v3 = ep[3];
        e[q][0]  = v0.x; e[q][1]  = v0.y; e[q][2]  = v0.z; e[q][3]  = v0.w;
        e[q][4]  = v1.x; e[q][5]  = v1.y; e[q][6]  = v1.z; e[q][7]  = v1.w;
        e[q][8]  = v2.x; e[q][9]  = v2.y; e[q][10] = v2.z; e[q][11] = v2.w;
        e[q][12] = v3.x; e[q][13] = v3.y; e[q][14] = v3.z; e[q][15] = v3.w;
    }

    float enc[4][NW];
    #pragma unroll
    for (int j = 0; j < NW; j++) {
        float wrow[16];
        {
            const float4* w4 = (const float4*)swq + j * 4;
            float4 w0 = w4[0], w1 = w4[1], w2 = w4[2], w3 = w4[3];
            wrow[0]  = w0.x; wrow[1]  = w0.y; wrow[2]  = w0.z; wrow[3]  = w0.w;
            wrow[4]  = w1.x; wrow[5]  = w1.y; wrow[6]  = w1.z; wrow[7]  = w1.w;
            wrow[8]  = w2.x; wrow[9]  = w2.y; wrow[10] = w2.z; wrow[11] = w2.w;
            wrow[12] = w3.x; wrow[13] = w3.y; wrow[14] = w3.z; wrow[15] = w3.w;
        }
        const float bt = sbt1[j];
        #pragma unroll
        for (int q = 0; q < 4; q++)
            enc[q][j] = __cosf(dot16aa(e[q], wrow, bt));
    }

    // phase 2: px in [j][g][q] layout, stores in layout order
    __half* pxp = px + ((size_t)b * S4 + s4) * 256;
    for (int j = 0; j < 16; j++) {
        uint2 pk[4];
        #pragma unroll
        for (int g = 0; g < 4; g++) {
            const int gj = g * 16 + j;
            float wrow[16];
            {
                const float4* w4 = (const float4*)swx + gj * 4;
                float4 w0 = w4[0], w1 = w4[1], w2 = w4[2], w3 = w4[3];
                wrow[0]  = w0.x; wrow[1]  = w0.y; wrow[2]  = w0.z; wrow[3]  = w0.w;
                wrow[4]  = w1.x; wrow[5]  = w1.y; wrow[6]  = w1.z; wrow[7]  = w1.w;
                wrow[8]  = w2.x; wrow[9]  = w2.y; wrow[10] = w2.z; wrow[11] = w2.w;
                wrow[12] = w3.x; wrow[13] = w3.y; wrow[14] = w3.z; wrow[15] = w3.w;
            }
            const float bt = sbt2[gj];
            float a0 = dot16aa(enc[0], wrow, bt);
            float a1 = dot16aa(enc[1], wrow, bt);
            float a2 = dot16aa(enc[2], wrow, bt);
            float a3 = dot16aa(enc[3], wrow, bt);
            __half2 lo = __floats2half2_rn(a0, a1);
            __half2 hi = __floats2half2_rn(a2, a3);
            pk[g].x = h2u(lo);
            pk[g].y = h2u(hi);
        }
        uint4 s0, s1;
        s0.x = pk[0].x; s0.y = pk[0].y; s0.z = pk[1].x; s0.w = pk[1].y;
        s1.x = pk[2].x; s1.y = pk[2].y; s1.z = pk[3].x; s1.w = pk[3].y;
        uint4* dst = (uint4*)pxp + j * 2;
        dst[0] = s0;
        dst[1] = s1;
    }
}

// ---------------------------------------------------------------------------
// Kernel B: fused recurrence + tag head, TWO BATCHES PER LANE packed as
// __half2 (low = even batch A, high = odd batch B). Wave = 4 rows x 2
// batches = 8 batches. All dots via v_pk_fma_f16 (__hfma2) — one instr
// serves both batches; halves never mix. DPP allgather moves packed regs
// (15 DPPs / 8 batches). Trans/state unpacked to f32 per batch.
// 256-thread workgroups = 4 independent waves (no barriers/LDS).
// launch_bounds min-waves stays 2 (>=256 VGPR budget; clamping spilled in R8).
// ---------------------------------------------------------------------------
__global__ __launch_bounds__(256, 2) void lstm_tag_kernel(
    const __half* __restrict__ px,
    const float* __restrict__ w_f, const float* __restrict__ w_i,
    const float* __restrict__ w_u, const float* __restrict__ w_o,
    const float* __restrict__ w_tag, const float* __restrict__ b_tag,
    float* __restrict__ out)
{
    const int lane  = threadIdx.x & 63;
    const int wid   = blockIdx.x * 4 + (threadIdx.x >> 6);  // 0..2047
    const int row   = lane >> 4;          // batch-pair sub-index within wave
    const int j     = lane & 15;          // hidden unit
    const int chunk = wid >> 5;           // 64 chunks
    const int b8    = wid & 31;           // group of 8 batches
    const int bA    = b8 * 8 + row * 2;   // even batch (low half)
    // bB = bA + 1 (high half)

    // xor map of the DPP allgather network (stages: ^1, ^2, ^7, ^8)
    const int XMAP[16] = {0,1,2,3,7,6,5,4,8,9,10,11,15,14,13,12};

    // h-weights for all 4 gates of unit j, XMAP order, duplicated per-half
    __half2 wrot2[4][16];
    {
        const float* wsrc[4] = {w_f, w_i, w_u, w_o};
        #pragma unroll
        for (int g = 0; g < 4; g++)
            #pragma unroll
            for (int m = 0; m < 16; m++) {
                float w = wsrc[g][j * 32 + 16 + (j ^ XMAP[m])];
                wrot2[g][m] = __floats2half2_rn(w, w);
            }
    }
    // tag weights for tags 4j..4j+3, XMAP order, duplicated per-half
    __half2 wtp2[4][16];
    __half2 btag2[4];
    #pragma unroll
    for (int t = 0; t < 4; t++) {
        #pragma unroll
        for (int m = 0; m < 16; m++) {
            float w = w_tag[(j * 4 + t) * 16 + (j ^ XMAP[m])];
            wtp2[t][m] = __floats2half2_rn(w, w);
        }
        float bt = b_tag[j * 4 + t];
        btag2[t] = __floats2half2_rn(bt, bt);
    }

    const int start_s4 = chunk * CH_S4;
    const int warm_s4  = (chunk == 0) ? 0 : (start_s4 - WARM_S4);
    const int end_s4   = start_s4 + CH_S4;
    const int emit0    = start_s4 * 4;     // first emitted timestep

    float cA = 0.f, cB = 0.f;
    uint32 hPu = 0;                        // packed (hA, hB), fp16

    // px: per (b,s4) 512B block; lane j reads 32B at offset j*32, two batches
    const uint4* pbA = (const uint4*)px + ((size_t)bA * S4 + warm_s4) * 32 + j * 2;
    const uint4* pbB = pbA + (size_t)S4 * 32;   // batch bA+1
    uint4 curA0 = pbA[0], curA1 = pbA[1];
    uint4 curB0 = pbB[0], curB1 = pbB[1];
    const int niters = end_s4 - warm_s4;

    float* outpA = out + ((size_t)emit0 * BATCH + bA) * TAGS + j * 4;
    float* outpB = outpA + TAGS;

#define ALLGATHER_U(hsrc, vv) do { \
    vv[0] = (hsrc); \
    vv[1] = DPPI(vv[0], 0xB1); \
    vv[2] = DPPI(vv[0], 0x4E); \
    vv[3] = DPPI(vv[1], 0x4E); \
    vv[4] = DPPI(vv[0], 0x141); \
    vv[5] = DPPI(vv[1], 0x141); \
    vv[6] = DPPI(vv[2], 0x141); \
    vv[7] = DPPI(vv[3], 0x141); \
    vv[8]  = DPPI(vv[0], 0x128); \
    vv[9]  = DPPI(vv[1], 0x128); \
    vv[10] = DPPI(vv[2], 0x128); \
    vv[11] = DPPI(vv[3], 0x128); \
    vv[12] = DPPI(vv[4], 0x128); \
    vv[13] = DPPI(vv[5], 0x128); \
    vv[14] = DPPI(vv[6], 0x128); \
    vv[15] = DPPI(vv[7], 0x128); \
} while (0)

#define TAG_EMIT(vv) do { \
    float lgA0, lgA1, lgA2, lgA3, lgB0, lgB1, lgB2, lgB3; \
    dot16h(vv, wtp2[0], btag2[0], lgA0, lgB0); \
    dot16h(vv, wtp2[1], btag2[1], lgA1, lgB1); \
    dot16h(vv, wtp2[2], btag2[2], lgA2, lgB2); \
    dot16h(vv, wtp2[3], btag2[3], lgA3, lgB3); \
    float pA = (__expf(lgA0) + __expf(lgA1)) + (__expf(lgA2) + __expf(lgA3)); \
    float pB = (__expf(lgB0) + __expf(lgB1)) + (__expf(lgB2) + __expf(lgB3)); \
    pA += DPPF(pA, 0x121); \
    pA += DPPF(pA, 0x122); \
    pA += DPPF(pA, 0x124); \
    pA += DPPF(pA, 0x128); \
    pB += DPPF(pB, 0x121); \
    pB += DPPF(pB, 0x122); \
    pB += DPPF(pB, 0x124); \
    pB += DPPF(pB, 0x128); \
    const float lpA = __logf(pA); \
    const float lpB = __logf(pB); \
    *(float4*)outpA = make_float4(lgA0 - lpA, lgA1 - lpA, lgA2 - lpA, lgA3 - lpA); \
    *(float4*)outpB = make_float4(lgB0 - lpB, lgB1 - lpB, lgB2 - lpB, lgB3 - lpB); \
    outpA += (size_t)BATCH * TAGS; \
    outpB += (size_t)BATCH * TAGS; \
} while (0)

    for (int it = 0; it < niters; it++) {
        const int nidx = (it < niters - 1) ? (it + 1) : it;
        uint4 nA0 = pbA[(size_t)nidx * 32];
        uint4 nA1 = pbA[(size_t)nidx * 32 + 1];
        uint4 nB0 = pbB[(size_t)nidx * 32];
        uint4 nB1 = pbB[(size_t)nidx * 32 + 1];

        const int sg_base = (warm_s4 + it) * 4;

        #pragma unroll
        for (int q = 0; q < 4; q++) {
            // ---- px words for this q: per gate, batch A and B ----
            const uint32 gA0 = (q < 2) ? curA0.x : curA0.y;
            const uint32 gA1 = (q < 2) ? curA0.z : curA0.w;
            const uint32 gA2 = (q < 2) ? curA1.x : curA1.y;
            const uint32 gA3 = (q < 2) ? curA1.z : curA1.w;
            const uint32 gB0 = (q < 2) ? curB0.x : curB0.y;
            const uint32 gB1 = (q < 2) ? curB0.z : curB0.w;
            const uint32 gB2 = (q < 2) ? curB1.x : curB1.y;
            const uint32 gB3 = (q < 2) ? curB1.z : curB1.w;
            uint32 px0, px1, px2, px3;     // packed (pxA, pxB) per gate
            if ((q & 1) == 0) {
                px0 = (gA0 & 0xFFFFu) | (gB0 << 16);
                px1 = (gA1 & 0xFFFFu) | (gB1 << 16);
                px2 = (gA2 & 0xFFFFu) | (gB2 << 16);
                px3 = (gA3 & 0xFFFFu) | (gB3 << 16);
            } else {
                px0 = (gA0 >> 16) | (gB0 & 0xFFFF0000u);
                px1 = (gA1 >> 16) | (gB1 & 0xFFFF0000u);
                px2 = (gA2 >> 16) | (gB2 & 0xFFFF0000u);
                px3 = (gA3 >> 16) | (gB3 & 0xFFFF0000u);
            }

            // ---- allgather packed h_{t-1} across each 16-lane row ----
            uint32 vv[16];
            ALLGATHER_U(hPu, vv);

            // ---- tag head for previous timestep (off the serial chain) ----
            const int sg = sg_base + q;
            if (sg > emit0) TAG_EMIT(vv);

            // ---- 4 gate pre-activations, both batches per instr ----
            float preA0, preA1, preA2, preA3, preB0, preB1, preB2, preB3;
            dot16h(vv, wrot2[0], u2h(px0), preA0, preB0);
            dot16h(vv, wrot2[1], u2h(px1), preA1, preB1);
            dot16h(vv, wrot2[2], u2h(px2), preA2, preB2);
            dot16h(vv, wrot2[3], u2h(px3), preA3, preB3);

            // ---- activations (f32): f,i,o sigmoid(cos); u tanh(cos) ----
            const float cvA0 = __cosf(preA0);
            const float cvA1 = __cosf(preA1);
            const float cvA2 = __cosf(preA2);
            const float cvA3 = __cosf(preA3);
            const float cvB0 = __cosf(preB0);
            const float cvB1 = __cosf(preB1);
            const float cvB2 = __cosf(preB2);
            const float cvB3 = __cosf(preB3);
            const float fvA = __builtin_amdgcn_rcpf(1.f + __expf(-cvA0));
            const float ivA = __builtin_amdgcn_rcpf(1.f + __expf(-cvA1));
            const float uvA = fmaf(2.f, __builtin_amdgcn_rcpf(1.f + __expf(-2.f * cvA2)), -1.f);
            const float ovA = __builtin_amdgcn_rcpf(1.f + __expf(-cvA3));
            const float fvB = __builtin_amdgcn_rcpf(1.f + __expf(-cvB0));
            const float ivB = __builtin_amdgcn_rcpf(1.f + __expf(-cvB1));
            const float uvB = fmaf(2.f, __builtin_amdgcn_rcpf(1.f + __expf(-2.f * cvB2)), -1.f);
            const float ovB = __builtin_amdgcn_rcpf(1.f + __expf(-cvB3));

            // ---- state update (both batches) ----
            cA = fmaf(fvA, cA, ivA * uvA);
            cB = fmaf(fvB, cB, ivB * uvB);
            const float thA = fmaf(2.f, __builtin_amdgcn_rcpf(1.f + __expf(-2.f * cA)), -1.f);
            const float thB = fmaf(2.f, __builtin_amdgcn_rcpf(1.f + __expf(-2.f * cB)), -1.f);
            const float hA = ovA * thA;
            const float hB = ovB * thB;
            hPu = h2u(__floats2half2_rn(hA, hB));
        }
        curA0 = nA0; curA1 = nA1;
        curB0 = nB0; curB1 = nB1;
    }

    // epilogue: tag for the chunk's final timestep
    {
        uint32 vv[16];
        ALLGATHER_U(hPu, vv);
        TAG_EMIT(vv);
    }
#undef ALLGATHER_U
#undef TAG_EMIT
}

extern "C" void kernel_launch(void* const* d_in, const int* in_sizes, int n_in,
                              void* d_out, int out_size, void* d_ws, size_t ws_size,
                              hipStream_t stream) {
    const int*   sentence = (const int*)d_in[0];
    const float* emb   = (const float*)d_in[1];
    const float* w_eq  = (const float*)d_in[2];
    const float* b_eq  = (const float*)d_in[3];
    const float* thc   = (const float*)d_in[4];
    const float* w_f   = (const float*)d_in[5];
    const float* b_f   = (const float*)d_in[6];
    const float* th_f  = (const float*)d_in[7];
    const float* w_i   = (const float*)d_in[8];
    const float* b_i   = (const float*)d_in[9];
    const float* th_i  = (const float*)d_in[10];
    const float* w_u   = (const float*)d_in[11];
    const float* b_u   = (const float*)d_in[12];
    const float* th_u  = (const float*)d_in[13];
    const float* w_o   = (const float*)d_in[14];
    const float* b_o   = (const float*)d_in[15];
    const float* th_o  = (const float*)d_in[16];
    const float* w_tag = (const float*)d_in[17];
    const float* b_tag = (const float*)d_in[18];

    __half* pxw = (__half*)d_ws;                 // 67,108,864 B
    float*  out = (float*)d_out;

    encode_px_kernel<<<dim3((S4 * BATCH) / 256), dim3(256), 0, stream>>>(
        sentence, emb, w_eq, b_eq, thc,
        w_f, b_f, th_f, w_i, b_i, th_i, w_u, b_u, th_u, w_o, b_o, th_o, pxw);
    lstm_tag_kernel<<<dim3(NCHUNK * (BATCH / 8) / 4), dim3(256), 0, stream>>>(
        pxw, w_f, w_i, w_u, w_o, w_tag, b_tag, out);
}